// Round 2
// baseline (1507.247 us; speedup 1.0000x reference)
//
#include <hip/hip_runtime.h>

// VectorQuantizer on MI355X — numpy-fp32-faithful argmin.
// z: (64,256,32,32) f32; emb: (1024,256) f32.
// out (f32): [0,16777216) z_q_out | [16777216] loss | [16777217,+65536) indices
//
// ws layout (bytes):
//   0      double loss_acc
//   64     int    widx[65536]          (262144 B)
//   262208 float  e2[1024]             (4096 B, numpy-pairwise fp32)
//   266304 float  embT[256*1024]       (emb transposed, [d][k])

#define VQ_LDS_BYTES 131328

// fl32(v*v) with a barrier so the product cannot be contracted into a later add.
__device__ __forceinline__ float sq_rnd(float v) {
  float y = v * v;
  asm volatile("" : "+v"(y));
  return y;
}

// Bit-replication of numpy pairwise_sum over 256 fp32 terms x[d] = fl(v[d]^2):
// n=256 -> fl( block(0..127) + block(128..255) ), each block = 8 accumulators
// r[j] = x[j] + x[8+j] + ... + x[120+j] (sequential fp32 adds), combined as
// ((r0+r1)+(r2+r3)) + ((r4+r5)+(r6+r7)).
__device__ float np_pw256_sq(const float* base, int stride) {
  float tot0, tot1;
  {
    const float* a = base;
    float r[8];
    #pragma unroll
    for (int j = 0; j < 8; ++j) r[j] = sq_rnd(a[j * stride]);
    #pragma unroll 1
    for (int i = 8; i < 128; i += 8) {
      #pragma unroll
      for (int j = 0; j < 8; ++j) r[j] += sq_rnd(a[(i + j) * stride]);
    }
    tot0 = ((r[0] + r[1]) + (r[2] + r[3])) + ((r[4] + r[5]) + (r[6] + r[7]));
  }
  {
    const float* a = base + 128 * stride;
    float r[8];
    #pragma unroll
    for (int j = 0; j < 8; ++j) r[j] = sq_rnd(a[j * stride]);
    #pragma unroll 1
    for (int i = 8; i < 128; i += 8) {
      #pragma unroll
      for (int j = 0; j < 8; ++j) r[j] += sq_rnd(a[(i + j) * stride]);
    }
    tot1 = ((r[0] + r[1]) + (r[2] + r[3])) + ((r[4] + r[5]) + (r[6] + r[7]));
  }
  return tot0 + tot1;
}

__global__ __launch_bounds__(256) void vq_prep(const float* __restrict__ emb,
                                               float* __restrict__ embT,
                                               float* __restrict__ e2) {
  const int g = blockIdx.x * 256 + threadIdx.x;  // 0..262143
  const int k = g & 1023;
  const int d = g >> 10;
  embT[d * 1024 + k] = emb[k * 256 + d];
  if (g < 1024) e2[g] = np_pw256_sq(emb + g * 256, 1);
}

// Pass 1: d32[k] = fl32( fl32(z2_np + e2_np[k]) - 2*dot_fma(k) ), argmin (first index).
// Block: 64 points x K=1024 (16 chunks of 64). LDS: zt[256][64] + et[256][64] + z2s[64].
__global__ __launch_bounds__(256) void vq_dist(const float* __restrict__ z,
                                               const float* __restrict__ embT,
                                               const float* __restrict__ e2,
                                               int* __restrict__ widx) {
  extern __shared__ float lds[];
  float* zt = lds;            // [d][p]  d-major, 64 points
  float* et = lds + 16384;    // [d][kk] d-major, 64 codes
  float* z2s = lds + 32768;   // [64] numpy-pairwise |z|^2

  const int tid = threadIdx.x;
  const int n0 = blockIdx.x << 6;
  const int bb = n0 >> 10;
  const int hw0 = n0 & 1023;
  const float* zb = z + bb * 262144 + hw0;

  {  // stage z tile: coalesced global, conflict-free LDS
    const int p = tid & 63;
    const int dg = tid >> 6;
    #pragma unroll 4
    for (int it = 0; it < 64; ++it) {
      const int d = dg * 64 + it;
      zt[d * 64 + p] = zb[d * 1024 + p];
    }
  }
  __syncthreads();
  if (tid < 64) z2s[tid] = np_pw256_sq(zt + tid, 64);
  __syncthreads();

  const int ty = tid >> 4;  // point group: p = 4*ty + i
  const int tx = tid & 15;  // code group:  kk = 4*tx + j
  float z2v[4];
  #pragma unroll
  for (int i = 0; i < 4; ++i) z2v[i] = z2s[ty * 4 + i];

  float m1[4];
  int i1[4];
  #pragma unroll
  for (int i = 0; i < 4; ++i) { m1[i] = 3.0e38f; i1[i] = 0; }

  for (int c = 0; c < 16; ++c) {
    __syncthreads();
    #pragma unroll 4
    for (int it = 0; it < 16; ++it) {
      const int g = it * 256 + tid;      // float4 slot 0..4095
      const int d = g >> 4;
      const int kk = (g & 15) << 2;
      *(float4*)&et[d * 64 + kk] = *(const float4*)&embT[d * 1024 + c * 64 + kk];
    }
    __syncthreads();

    float e2v[4];
    #pragma unroll
    for (int j = 0; j < 4; ++j) e2v[j] = e2[c * 64 + tx * 4 + j];

    float acc[4][4];
    #pragma unroll
    for (int i = 0; i < 4; ++i)
      #pragma unroll
      for (int j = 0; j < 4; ++j) acc[i][j] = 0.f;

    // Sequential fp32 FMA chain over d = 0..255 (BLAS-microkernel order).
    #pragma unroll 2
    for (int d = 0; d < 256; d += 4) {
      float zr[4][4], er[4][4];
      #pragma unroll
      for (int cc = 0; cc < 4; ++cc) {
        const float4 a = *(const float4*)&zt[(d + cc) * 64 + ty * 4];
        zr[cc][0] = a.x; zr[cc][1] = a.y; zr[cc][2] = a.z; zr[cc][3] = a.w;
        const float4 b = *(const float4*)&et[(d + cc) * 64 + tx * 4];
        er[cc][0] = b.x; er[cc][1] = b.y; er[cc][2] = b.z; er[cc][3] = b.w;
      }
      #pragma unroll
      for (int cc = 0; cc < 4; ++cc)
        #pragma unroll
        for (int i = 0; i < 4; ++i)
          #pragma unroll
          for (int j = 0; j < 4; ++j)
            acc[i][j] = fmaf(zr[cc][i], er[cc][j], acc[i][j]);
    }

    #pragma unroll
    for (int i = 0; i < 4; ++i) {
      #pragma unroll
      for (int j = 0; j < 4; ++j) {
        const float t1 = z2v[i] + e2v[j];        // fl32(z2 + e2[k])
        const float s = t1 - 2.0f * acc[i][j];   // fl32(t1 - 2*dot)
        const int k = c * 64 + tx * 4 + j;       // within-thread k ascending
        if (s < m1[i]) { m1[i] = s; i1[i] = k; }
      }
    }
  }

  // argmin merge across the 16 tx-lanes: lower value, tie -> lower index
  #pragma unroll
  for (int mask = 1; mask < 16; mask <<= 1) {
    #pragma unroll
    for (int i = 0; i < 4; ++i) {
      const float om1 = __shfl_xor(m1[i], mask);
      const int oi = __shfl_xor(i1[i], mask);
      if (om1 < m1[i] || (om1 == m1[i] && oi < i1[i])) {
        m1[i] = om1;
        i1[i] = oi;
      }
    }
  }

  if (tx == 0) {
    #pragma unroll
    for (int i = 0; i < 4; ++i) widx[n0 + ty * 4 + i] = i1[i];
  }
}

// z_q_out = fl(z + fl(z_q - z)) + fp64 loss accumulation.
__global__ __launch_bounds__(256) void vq_out(const float* __restrict__ z,
                                              const float* __restrict__ emb,
                                              const int* __restrict__ widx,
                                              float* __restrict__ out,
                                              double* __restrict__ acc) {
  const int g = blockIdx.x * 256 + threadIdx.x;  // 0..4194303
  const int o = g * 4;
  const int hw = o & 1023;
  const int d = (o >> 10) & 255;
  const int bb = o >> 18;
  const int nb = (bb << 10) | hw;
  const int4 id4 = *(const int4*)&widx[nb];
  const float4 zv = *(const float4*)&z[o];
  float4 qv;
  qv.x = emb[id4.x * 256 + d];
  qv.y = emb[id4.y * 256 + d];
  qv.z = emb[id4.z * 256 + d];
  qv.w = emb[id4.w * 256 + d];
  float dx = qv.x - zv.x, dy = qv.y - zv.y, dz = qv.z - zv.z, dw = qv.w - zv.w;
  asm volatile("" : "+v"(dx), "+v"(dy), "+v"(dz), "+v"(dw));
  float4 ov;
  ov.x = zv.x + dx; ov.y = zv.y + dy; ov.z = zv.z + dz; ov.w = zv.w + dw;
  *(float4*)&out[o] = ov;
  double s = (double)dx * dx + (double)dy * dy + (double)dz * dz + (double)dw * dw;
  #pragma unroll
  for (int off = 32; off > 0; off >>= 1) s += __shfl_down(s, off);
  if ((threadIdx.x & 63) == 0) atomicAdd(acc, s);
}

__global__ __launch_bounds__(256) void vq_fin(const int* __restrict__ widx,
                                              const double* __restrict__ acc,
                                              float* __restrict__ out) {
  const int t = blockIdx.x * 256 + threadIdx.x;
  if (t < 65536) out[16777217 + t] = (float)widx[t];
  if (t == 0) out[16777216] = (float)(1.25 * (*acc) * (1.0 / 16777216.0));
}

extern "C" void kernel_launch(void* const* d_in, const int* in_sizes, int n_in,
                              void* d_out, int out_size, void* d_ws, size_t ws_size,
                              hipStream_t stream) {
  const float* z = (const float*)d_in[0];
  const float* emb = (const float*)d_in[1];
  float* out = (float*)d_out;
  char* ws = (char*)d_ws;
  double* acc = (double*)(ws);
  int* widx = (int*)(ws + 64);
  float* e2 = (float*)(ws + 64 + 262144);
  float* embT = (float*)(ws + 64 + 262144 + 4096);

  hipFuncSetAttribute(reinterpret_cast<const void*>(vq_dist),
                      hipFuncAttributeMaxDynamicSharedMemorySize, VQ_LDS_BYTES);

  hipMemsetAsync(ws, 0, 16, stream);
  vq_prep<<<1024, 256, 0, stream>>>(emb, embT, e2);
  vq_dist<<<1024, 256, VQ_LDS_BYTES, stream>>>(z, embT, e2, widx);
  vq_out<<<16384, 256, 0, stream>>>(z, emb, widx, out, acc);
  vq_fin<<<256, 256, 0, stream>>>(widx, acc, out);
}

// Round 3
// 661.643 us; speedup vs baseline: 2.2780x; 2.2780x over previous
//
#include <hip/hip_runtime.h>

// VectorQuantizer on MI355X — numpy-fp32-faithful argmin, round 3 (perf).
// z: (64,256,32,32) f32; emb: (1024,256) f32.
// out (f32): [0,16777216) z_q_out | [16777216] loss | [16777217,+65536) indices
//
// ws layout (bytes):
//   0       double loss_acc                  (memset 0)
//   64      ull    keys[65536]               (memset 0xFF; (s_bits<<10)|k)
//   524352  float  e2[1024]                  (numpy-pairwise fp32)
//   528448  float  z2[65536]                 (numpy-pairwise fp32)
//   790592  float  embT[256*1024]            (emb transposed, [d][k])

// fl32(v*v) with a barrier so the product cannot be contracted into a later add.
__device__ __forceinline__ float sq_rnd(float v) {
  float y = v * v;
  asm volatile("" : "+v"(y));
  return y;
}

// numpy pairwise_sum over 256 fp32 squared terms (8-accumulator blocks of 128).
__device__ float np_pw256_sq(const float* base, int stride) {
  float tot0, tot1;
  {
    const float* a = base;
    float r[8];
    #pragma unroll
    for (int j = 0; j < 8; ++j) r[j] = sq_rnd(a[j * stride]);
    #pragma unroll 1
    for (int i = 8; i < 128; i += 8) {
      #pragma unroll
      for (int j = 0; j < 8; ++j) r[j] += sq_rnd(a[(i + j) * stride]);
    }
    tot0 = ((r[0] + r[1]) + (r[2] + r[3])) + ((r[4] + r[5]) + (r[6] + r[7]));
  }
  {
    const float* a = base + 128 * stride;
    float r[8];
    #pragma unroll
    for (int j = 0; j < 8; ++j) r[j] = sq_rnd(a[j * stride]);
    #pragma unroll 1
    for (int i = 8; i < 128; i += 8) {
      #pragma unroll
      for (int j = 0; j < 8; ++j) r[j] += sq_rnd(a[(i + j) * stride]);
    }
    tot1 = ((r[0] + r[1]) + (r[2] + r[3])) + ((r[4] + r[5]) + (r[6] + r[7]));
  }
  return tot0 + tot1;
}

__global__ __launch_bounds__(256) void vq_prep(const float* __restrict__ emb,
                                               float* __restrict__ embT,
                                               float* __restrict__ e2) {
  const int g = blockIdx.x * 256 + threadIdx.x;  // 0..262143
  const int k = g & 1023;
  const int d = g >> 10;
  embT[d * 1024 + k] = emb[k * 256 + d];
  if (g < 1024) e2[g] = np_pw256_sq(emb + g * 256, 1);
}

// |z|^2 per point, numpy-pairwise. 4 points/thread via float4 along hw.
__global__ __launch_bounds__(256) void vq_z2(const float* __restrict__ z,
                                             float* __restrict__ z2) {
  const int t4 = blockIdx.x * 256 + threadIdx.x;  // 0..16383
  const int n0 = t4 * 4;
  const int bb = n0 >> 10, hw = n0 & 1023;
  const float* zp = z + bb * 262144 + hw;
  float r0[4][8], r1[4][8];
  #pragma unroll
  for (int p = 0; p < 4; ++p)
    #pragma unroll
    for (int j = 0; j < 8; ++j) { r0[p][j] = 0.f; r1[p][j] = 0.f; }
  #pragma unroll 1
  for (int d8 = 0; d8 < 128; d8 += 8) {
    #pragma unroll
    for (int j = 0; j < 8; ++j) {
      const float4 v = *(const float4*)&zp[(d8 + j) * 1024];
      r0[0][j] += sq_rnd(v.x); r0[1][j] += sq_rnd(v.y);
      r0[2][j] += sq_rnd(v.z); r0[3][j] += sq_rnd(v.w);
    }
  }
  #pragma unroll 1
  for (int d8 = 128; d8 < 256; d8 += 8) {
    #pragma unroll
    for (int j = 0; j < 8; ++j) {
      const float4 v = *(const float4*)&zp[(d8 + j) * 1024];
      r1[0][j] += sq_rnd(v.x); r1[1][j] += sq_rnd(v.y);
      r1[2][j] += sq_rnd(v.z); r1[3][j] += sq_rnd(v.w);
    }
  }
  #pragma unroll
  for (int p = 0; p < 4; ++p) {
    const float t0 = ((r0[p][0] + r0[p][1]) + (r0[p][2] + r0[p][3])) +
                     ((r0[p][4] + r0[p][5]) + (r0[p][6] + r0[p][7]));
    const float t1 = ((r1[p][0] + r1[p][1]) + (r1[p][2] + r1[p][3])) +
                     ((r1[p][4] + r1[p][5]) + (r1[p][6] + r1[p][7]));
    z2[n0 + p] = t0 + t1;
  }
}

// Distance + argmin. Block tile: 128 points x 128 codes, 256 threads, 8x8 micro.
// e LDS layout pair-interleaved for conflict-free b64 reads; z reads broadcast.
// Cross-block merge: atomicMin on (float_bits(s)<<10)|k (s>0 -> monotone bits).
__global__ __launch_bounds__(256, 2) void vq_dist(const float* __restrict__ z,
                                                  const float* __restrict__ embT,
                                                  const float* __restrict__ e2,
                                                  const float* __restrict__ z2,
                                                  unsigned long long* __restrict__ keys) {
  __shared__ float zc[32 * 128];
  __shared__ float ec[32 * 128];
  const int tid = threadIdx.x;
  const int bk = blockIdx.x & 7;
  const int bp = blockIdx.x >> 3;
  const int n0 = bp * 128;
  const int bb = n0 >> 10;
  const int hw0 = n0 & 1023;
  const int k0 = bk * 128;
  const float* zb = z + bb * 262144 + hw0;
  const float* eb = embT + k0;

  const int ti = tid >> 4;        // point group: p0 = ti*8
  const int tj = tid & 15;        // code group:  kk0 = tj*8
  const int p0 = ti * 8;
  const int sq = (tid & 31) * 4;  // staging column
  const int sd = tid >> 5;        // staging row base

  float acc[8][8];
  #pragma unroll
  for (int i = 0; i < 8; ++i)
    #pragma unroll
    for (int j = 0; j < 8; ++j) acc[i][j] = 0.f;

  for (int ch = 0; ch < 8; ++ch) {
    __syncthreads();
    #pragma unroll
    for (int pass = 0; pass < 4; ++pass) {
      const int dd = pass * 8 + sd;
      const int d = ch * 32 + dd;
      *(float4*)&zc[dd * 128 + sq] = *(const float4*)&zb[d * 1024 + sq];
      const float4 ev = *(const float4*)&eb[d * 1024 + sq];
      #pragma unroll
      for (int e = 0; e < 4; ++e) {  // scatter to pair-interleaved layout
        const int c = sq + e;
        ec[dd * 128 + ((c & 7) >> 1) * 32 + (c >> 3) * 2 + (c & 1)] =
            ((const float*)&ev)[e];
      }
    }
    __syncthreads();
    #pragma unroll 2
    for (int dd = 0; dd < 32; ++dd) {
      const float4 za = *(const float4*)&zc[dd * 128 + p0];
      const float4 zb4 = *(const float4*)&zc[dd * 128 + p0 + 4];
      const float2 e01 = *(const float2*)&ec[dd * 128 + tj * 2];
      const float2 e23 = *(const float2*)&ec[dd * 128 + 32 + tj * 2];
      const float2 e45 = *(const float2*)&ec[dd * 128 + 64 + tj * 2];
      const float2 e67 = *(const float2*)&ec[dd * 128 + 96 + tj * 2];
      const float zr[8] = {za.x, za.y, za.z, za.w, zb4.x, zb4.y, zb4.z, zb4.w};
      const float er[8] = {e01.x, e01.y, e23.x, e23.y, e45.x, e45.y, e67.x, e67.y};
      #pragma unroll
      for (int i = 0; i < 8; ++i)
        #pragma unroll
        for (int j = 0; j < 8; ++j)
          acc[i][j] = fmaf(zr[i], er[j], acc[i][j]);  // d-sequential chain
    }
  }

  float e2v[8];
  #pragma unroll
  for (int j = 0; j < 8; ++j) e2v[j] = e2[k0 + tj * 8 + j];

  float m[8];
  int id[8];
  #pragma unroll
  for (int i = 0; i < 8; ++i) {
    const float z2i = z2[n0 + p0 + i];
    float mm = 3.4e38f;
    int kk = 0;
    #pragma unroll
    for (int j = 0; j < 8; ++j) {  // k ascending -> first-index tie-break
      const float t1 = z2i + e2v[j];
      const float s = fmaf(-2.f, acc[i][j], t1);  // == fl(t1 - 2*acc)
      if (s < mm) { mm = s; kk = k0 + tj * 8 + j; }
    }
    m[i] = mm;
    id[i] = kk;
  }
  #pragma unroll
  for (int mask = 1; mask < 16; mask <<= 1) {
    #pragma unroll
    for (int i = 0; i < 8; ++i) {
      const float om = __shfl_xor(m[i], mask);
      const int oi = __shfl_xor(id[i], mask);
      if (om < m[i] || (om == m[i] && oi < id[i])) { m[i] = om; id[i] = oi; }
    }
  }
  if (tj == 0) {
    #pragma unroll
    for (int i = 0; i < 8; ++i) {
      const unsigned long long key =
          ((unsigned long long)__float_as_uint(m[i]) << 10) | (unsigned)id[i];
      atomicMin(&keys[n0 + p0 + i], key);
    }
  }
}

// Output + loss. Block = 64 points: gather 64 emb rows into LDS (row-coalesced),
// then transpose-read (stride 260: uniform banks, 16B-aligned) + coalesced write.
#define OUT_LDS_BYTES 66560
__global__ __launch_bounds__(256) void vq_out(const float* __restrict__ z,
                                              const float* __restrict__ emb,
                                              const unsigned long long* __restrict__ keys,
                                              float* __restrict__ out,
                                              double* __restrict__ acc) {
  extern __shared__ float rows[];  // [64][260]
  const int tid = threadIdx.x;
  const int w = tid >> 6, l = tid & 63;
  const int n0 = blockIdx.x << 6;
  const int bb = n0 >> 10, hw0 = n0 & 1023;

  #pragma unroll 4
  for (int rr = 0; rr < 16; ++rr) {
    const int r = rr * 4 + w;
    const int idx = (int)(keys[n0 + r] & 1023ULL);
    const float4 ev = *(const float4*)&emb[idx * 256 + l * 4];
    *(float4*)&rows[r * 260 + l * 4] = ev;
  }
  __syncthreads();

  const int zofs = bb * 262144 + hw0 + l;
  const float* zp = z + zofs;
  float* op = out + zofs;
  double ls = 0.0;
  #pragma unroll 2
  for (int i16 = 0; i16 < 16; ++i16) {
    const int d4 = w * 64 + i16 * 4;
    const float4 q4 = *(const float4*)&rows[l * 260 + d4];
    #pragma unroll
    for (int e = 0; e < 4; ++e) {
      const int d = d4 + e;
      const float zv = zp[d * 1024];
      const float qv = ((const float*)&q4)[e];
      float df = qv - zv;
      asm volatile("" : "+v"(df));
      op[d * 1024] = zv + df;  // fl(z + fl(z_q - z))
      ls += (double)df * df;
    }
  }
  #pragma unroll
  for (int off = 32; off > 0; off >>= 1) ls += __shfl_down(ls, off);
  if (l == 0) atomicAdd(acc, ls);
}

__global__ __launch_bounds__(256) void vq_fin(const unsigned long long* __restrict__ keys,
                                              const double* __restrict__ acc,
                                              float* __restrict__ out) {
  const int t = blockIdx.x * 256 + threadIdx.x;
  if (t < 65536) out[16777217 + t] = (float)(int)(keys[t] & 1023ULL);
  if (t == 0) out[16777216] = (float)(1.25 * (*acc) * (1.0 / 16777216.0));
}

extern "C" void kernel_launch(void* const* d_in, const int* in_sizes, int n_in,
                              void* d_out, int out_size, void* d_ws, size_t ws_size,
                              hipStream_t stream) {
  const float* z = (const float*)d_in[0];
  const float* emb = (const float*)d_in[1];
  float* out = (float*)d_out;
  char* ws = (char*)d_ws;
  double* acc = (double*)(ws);
  unsigned long long* keys = (unsigned long long*)(ws + 64);
  float* e2 = (float*)(ws + 524352);
  float* z2 = (float*)(ws + 528448);
  float* embT = (float*)(ws + 790592);

  hipFuncSetAttribute(reinterpret_cast<const void*>(vq_out),
                      hipFuncAttributeMaxDynamicSharedMemorySize, OUT_LDS_BYTES);

  hipMemsetAsync(ws, 0, 64, stream);
  hipMemsetAsync(ws + 64, 0xFF, 65536 * 8, stream);
  vq_prep<<<1024, 256, 0, stream>>>(emb, embT, e2);
  vq_z2<<<64, 256, 0, stream>>>(z, z2);
  vq_dist<<<4096, 256, 0, stream>>>(z, embT, e2, z2, keys);
  vq_out<<<1024, 256, OUT_LDS_BYTES, stream>>>(z, emb, keys, out, acc);
  vq_fin<<<256, 256, 0, stream>>>(keys, acc, out);
}

// Round 5
// 560.606 us; speedup vs baseline: 2.6886x; 1.1802x over previous
//
#include <hip/hip_runtime.h>

// VectorQuantizer on MI355X — round 5: f16-MFMA screening + exact fp32 rescore.
// (round-4 B-tile swizzle store/read mismatch fixed: store at i*16, data octet i^(r&7))
// z: (64,256,32,32) f32; emb: (1024,256) f32.
// out (f32): [0,16777216) z_q_out | [16777216] loss | [16777217,+65536) indices
//
// ws layout (bytes):
//   0        double   loss_acc                 (memset 0)
//   64       int      widx[65536]
//   262208   float    e2[1024]                 (numpy-pairwise fp32)
//   266304   float    z2[65536]                (numpy-pairwise fp32)
//   528448   int      gcnt[65536]
//   790592   ushort   gcand[65536*16]
//   2887744  _Float16 Ef[1024*256]             (f16 RNE copy of emb)

typedef _Float16 f16x8 __attribute__((ext_vector_type(8)));
typedef float f32x4 __attribute__((ext_vector_type(4)));

#define VQ_W 1.5e-3f

// fl32(v*v) with a barrier so the product cannot be contracted into a later add.
__device__ __forceinline__ float sq_rnd(float v) {
  float y = v * v;
  asm volatile("" : "+v"(y));
  return y;
}

// numpy pairwise_sum over 256 fp32 squared terms (8-accumulator blocks of 128).
__device__ float np_pw256_sq(const float* base, int stride) {
  float tot0, tot1;
  {
    const float* a = base;
    float r[8];
    #pragma unroll
    for (int j = 0; j < 8; ++j) r[j] = sq_rnd(a[j * stride]);
    #pragma unroll 1
    for (int i = 8; i < 128; i += 8) {
      #pragma unroll
      for (int j = 0; j < 8; ++j) r[j] += sq_rnd(a[(i + j) * stride]);
    }
    tot0 = ((r[0] + r[1]) + (r[2] + r[3])) + ((r[4] + r[5]) + (r[6] + r[7]));
  }
  {
    const float* a = base + 128 * stride;
    float r[8];
    #pragma unroll
    for (int j = 0; j < 8; ++j) r[j] = sq_rnd(a[j * stride]);
    #pragma unroll 1
    for (int i = 8; i < 128; i += 8) {
      #pragma unroll
      for (int j = 0; j < 8; ++j) r[j] += sq_rnd(a[(i + j) * stride]);
    }
    tot1 = ((r[0] + r[1]) + (r[2] + r[3])) + ((r[4] + r[5]) + (r[6] + r[7]));
  }
  return tot0 + tot1;
}

__global__ __launch_bounds__(256) void vq_prep(const float* __restrict__ emb,
                                               _Float16* __restrict__ Ef,
                                               float* __restrict__ e2) {
  const int g = blockIdx.x * 256 + threadIdx.x;  // 0..262143
  Ef[g] = (_Float16)emb[g];                      // RNE v_cvt_f16_f32
  if (g < 1024) e2[g] = np_pw256_sq(emb + g * 256, 1);
}

// |z|^2 per point, numpy-pairwise. 4 points/thread via float4 along hw. (r3-verified)
__global__ __launch_bounds__(256) void vq_z2(const float* __restrict__ z,
                                             float* __restrict__ z2) {
  const int t4 = blockIdx.x * 256 + threadIdx.x;  // 0..16383
  const int n0 = t4 * 4;
  const int bb = n0 >> 10, hw = n0 & 1023;
  const float* zp = z + bb * 262144 + hw;
  float r0[4][8], r1[4][8];
  #pragma unroll
  for (int p = 0; p < 4; ++p)
    #pragma unroll
    for (int j = 0; j < 8; ++j) { r0[p][j] = 0.f; r1[p][j] = 0.f; }
  #pragma unroll 1
  for (int d8 = 0; d8 < 128; d8 += 8) {
    #pragma unroll
    for (int j = 0; j < 8; ++j) {
      const float4 v = *(const float4*)&zp[(d8 + j) * 1024];
      r0[0][j] += sq_rnd(v.x); r0[1][j] += sq_rnd(v.y);
      r0[2][j] += sq_rnd(v.z); r0[3][j] += sq_rnd(v.w);
    }
  }
  #pragma unroll 1
  for (int d8 = 128; d8 < 256; d8 += 8) {
    #pragma unroll
    for (int j = 0; j < 8; ++j) {
      const float4 v = *(const float4*)&zp[(d8 + j) * 1024];
      r1[0][j] += sq_rnd(v.x); r1[1][j] += sq_rnd(v.y);
      r1[2][j] += sq_rnd(v.z); r1[3][j] += sq_rnd(v.w);
    }
  }
  #pragma unroll
  for (int p = 0; p < 4; ++p) {
    const float t0 = ((r0[p][0] + r0[p][1]) + (r0[p][2] + r0[p][3])) +
                     ((r0[p][4] + r0[p][5]) + (r0[p][6] + r0[p][7]));
    const float t1 = ((r1[p][0] + r1[p][1]) + (r1[p][2] + r1[p][3])) +
                     ((r1[p][4] + r1[p][5]) + (r1[p][6] + r1[p][7]));
    z2[n0 + p] = t0 + t1;
  }
}

// Screening: f16 MFMA, block = 64 points x all 1024 codes (8 chunks of 128).
// A resident in LDS [64 pts][256 k] f16, rows XOR-swizzled by (row&7).
// B staged per k-step, same XOR swizzle: LDS position p of row r holds k-octet
// p^(r&7); fragment read at pos j^(r&7) retrieves octet j.
// s~ = fl(fl(z2+e2) - 2*dot~); candidates: s~ <= runmin + W -> LDS lists.
__global__ __launch_bounds__(256, 3) void vq_screen(
    const float* __restrict__ z, const _Float16* __restrict__ Ef,
    const float* __restrict__ e2, const float* __restrict__ z2,
    int* __restrict__ gcnt, unsigned short* __restrict__ gcand) {
  __shared__ __align__(16) char smem[51712];
  // [0,32768) A; [32768,49152) B; 49152 runminU[64]; 49408 cnt[64]; 49664 cand[64][16]
  unsigned* runminU = (unsigned*)(smem + 49152);
  int* cnt = (int*)(smem + 49408);
  unsigned short* cand = (unsigned short*)(smem + 49664);

  const int tid = threadIdx.x;
  const int blk = blockIdx.x;
  const int n0 = blk * 64;
  const int bb = blk >> 4;
  const int hw0 = (blk & 15) * 64;
  const float* zb = z + bb * 262144 + hw0;

  if (tid < 64) { runminU[tid] = 0x7F800000u; cnt[tid] = 0; }

  {  // A stage: convert z tile to f16, swizzled rows (one-time)
    const int p = tid & 63, dh = tid >> 6;
    #pragma unroll
    for (int dq = 0; dq < 8; ++dq) {
      const int d0 = dh * 64 + dq * 8;
      f16x8 hv;
      #pragma unroll
      for (int j = 0; j < 8; ++j) hv[j] = (_Float16)zb[(d0 + j) * 1024 + p];
      *(f16x8*)&smem[p * 512 + ((d0 * 2) ^ ((p & 7) * 16))] = hv;
    }
  }

  const int l = tid & 63;
  const int ln = l & 15;
  const int q = l >> 4;
  const int wc = tid >> 6;        // col-wave: cols wc*32 .. +32
  const int xr = (l & 7) * 16;

  float z2r[4][4];
  #pragma unroll
  for (int fi = 0; fi < 4; ++fi)
    #pragma unroll
    for (int rg = 0; rg < 4; ++rg)
      z2r[fi][rg] = z2[n0 + fi * 16 + q * 4 + rg];

  f32x4 acc[4][2];
  #pragma unroll
  for (int fi = 0; fi < 4; ++fi)
    #pragma unroll
    for (int fj = 0; fj < 2; ++fj) acc[fi][fj] = (f32x4){0.f, 0.f, 0.f, 0.f};

  for (int cc = 0; cc < 8; ++cc) {
    for (int ks = 0; ks < 4; ++ks) {
      __syncthreads();
      #pragma unroll
      for (int it = 0; it < 4; ++it) {  // stage B tile 128 codes x 64 k (swizzled)
        const int c2 = it * 256 + tid;
        const int r = c2 >> 3, i = c2 & 7;
        const int isw = i ^ (r & 7);
        const f16x8 ev =
            *(const f16x8*)&Ef[(cc * 128 + r) * 256 + ks * 64 + isw * 8];
        *(f16x8*)&smem[32768 + r * 128 + i * 16] = ev;  // pos i <- octet i^(r&7)
      }
      __syncthreads();
      #pragma unroll
      for (int sl = 0; sl < 2; ++sl) {
        const int cb = (sl * 64 + q * 16) ^ xr;
        f16x8 aF[4], bF[2];
        #pragma unroll
        for (int fi = 0; fi < 4; ++fi)
          aF[fi] = *(const f16x8*)&smem[(fi * 16 + ln) * 512 + ks * 128 + cb];
        #pragma unroll
        for (int fj = 0; fj < 2; ++fj)
          bF[fj] = *(const f16x8*)&smem[32768 + (wc * 32 + fj * 16 + ln) * 128 + cb];
        #pragma unroll
        for (int fi = 0; fi < 4; ++fi)
          #pragma unroll
          for (int fj = 0; fj < 2; ++fj)
            acc[fi][fj] = __builtin_amdgcn_mfma_f32_16x16x32_f16(
                aF[fi], bF[fj], acc[fi][fj], 0, 0, 0);
      }
    }
    // epilogue: scores, running row-min, candidate collection
    const int c0 = cc * 128 + wc * 32 + ln;
    const float e2v0 = e2[c0];
    const float e2v1 = e2[c0 + 16];
    float sv[4][2][4];
    #pragma unroll
    for (int fi = 0; fi < 4; ++fi)
      #pragma unroll
      for (int rg = 0; rg < 4; ++rg) {
        sv[fi][0][rg] = fmaf(-2.f, acc[fi][0][rg], z2r[fi][rg] + e2v0);
        sv[fi][1][rg] = fmaf(-2.f, acc[fi][1][rg], z2r[fi][rg] + e2v1);
      }
    #pragma unroll
    for (int fi = 0; fi < 4; ++fi)
      #pragma unroll
      for (int rg = 0; rg < 4; ++rg) {
        float rm = fminf(sv[fi][0][rg], sv[fi][1][rg]);
        rm = fminf(rm, __shfl_xor(rm, 1));
        rm = fminf(rm, __shfl_xor(rm, 2));
        rm = fminf(rm, __shfl_xor(rm, 4));
        rm = fminf(rm, __shfl_xor(rm, 8));
        if (ln == 0)
          atomicMin(&runminU[fi * 16 + q * 4 + rg], __float_as_uint(rm));
      }
    __syncthreads();
    #pragma unroll
    for (int fi = 0; fi < 4; ++fi)
      #pragma unroll
      for (int rg = 0; rg < 4; ++rg) {
        const int row = fi * 16 + q * 4 + rg;
        const float thr = __uint_as_float(runminU[row]) + VQ_W;
        #pragma unroll
        for (int fj = 0; fj < 2; ++fj)
          if (sv[fi][fj][rg] <= thr) {
            const int slot = atomicAdd(&cnt[row], 1);
            if (slot < 16) cand[row * 16 + slot] = (unsigned short)(c0 + fj * 16);
          }
      }
    #pragma unroll
    for (int fi = 0; fi < 4; ++fi)
      #pragma unroll
      for (int fj = 0; fj < 2; ++fj) acc[fi][fj] = (f32x4){0.f, 0.f, 0.f, 0.f};
  }
  __syncthreads();
  if (tid < 64) gcnt[n0 + tid] = cnt[tid];
  {
    const int rr = tid >> 2, si = (tid & 3) * 4;
    *(uint2*)&gcand[(n0 + rr) * 16 + si] = *(const uint2*)&cand[rr * 16 + si];
  }
}

// Exact fp32 rescore of candidates (sequential fmaf chain, r3-verified semantics).
__global__ __launch_bounds__(256) void vq_rescore(
    const float* __restrict__ z, const float* __restrict__ emb,
    const float* __restrict__ e2, const float* __restrict__ z2,
    const int* __restrict__ gcnt, const unsigned short* __restrict__ gcand,
    int* __restrict__ widx) {
  const int n = blockIdx.x * 256 + threadIdx.x;
  const int c = gcnt[n];
  if (c == 1) { widx[n] = gcand[n * 16]; return; }
  const int bb = n >> 10, hw = n & 1023;
  const float* zp = z + bb * 262144 + hw;
  const float z2n = z2[n];
  float best = 3.4e38f;
  int bi = 0;
  if (c <= 16) {
    for (int s = 0; s < c; ++s) {
      const int k = gcand[n * 16 + s];
      const float* ep = emb + k * 256;
      float a = 0.f;
      #pragma unroll 4
      for (int d = 0; d < 256; ++d) a = fmaf(zp[d * 1024], ep[d], a);
      const float sv = fmaf(-2.f, a, z2n + e2[k]);
      if (sv < best || (sv == best && k < bi)) { best = sv; bi = k; }
    }
  } else {  // overflow fallback: exact full scan (ascending k -> first-index)
    for (int k = 0; k < 1024; ++k) {
      const float* ep = emb + k * 256;
      float a = 0.f;
      #pragma unroll 4
      for (int d = 0; d < 256; ++d) a = fmaf(zp[d * 1024], ep[d], a);
      const float sv = fmaf(-2.f, a, z2n + e2[k]);
      if (sv < best) { best = sv; bi = k; }
    }
  }
  widx[n] = bi;
}

// Output + loss (r3-verified). Gather 64 emb rows into LDS row-coalesced, then
// transpose-read (stride 260) + coalesced global write.
#define OUT_LDS_BYTES 66560
__global__ __launch_bounds__(256) void vq_out(const float* __restrict__ z,
                                              const float* __restrict__ emb,
                                              const int* __restrict__ widx,
                                              float* __restrict__ out,
                                              double* __restrict__ acc) {
  extern __shared__ float rows[];  // [64][260]
  const int tid = threadIdx.x;
  const int w = tid >> 6, l = tid & 63;
  const int n0 = blockIdx.x << 6;
  const int bb = n0 >> 10, hw0 = n0 & 1023;

  #pragma unroll 4
  for (int rr = 0; rr < 16; ++rr) {
    const int r = rr * 4 + w;
    const int idx = widx[n0 + r];
    const float4 ev = *(const float4*)&emb[idx * 256 + l * 4];
    *(float4*)&rows[r * 260 + l * 4] = ev;
  }
  __syncthreads();

  const int zofs = bb * 262144 + hw0 + l;
  const float* zp = z + zofs;
  float* op = out + zofs;
  double ls = 0.0;
  #pragma unroll 2
  for (int i16 = 0; i16 < 16; ++i16) {
    const int d4 = w * 64 + i16 * 4;
    const float4 q4 = *(const float4*)&rows[l * 260 + d4];
    #pragma unroll
    for (int e = 0; e < 4; ++e) {
      const int d = d4 + e;
      const float zv = zp[d * 1024];
      const float qv = ((const float*)&q4)[e];
      float df = qv - zv;
      asm volatile("" : "+v"(df));
      op[d * 1024] = zv + df;  // fl(z + fl(z_q - z))
      ls += (double)df * df;
    }
  }
  #pragma unroll
  for (int off = 32; off > 0; off >>= 1) ls += __shfl_down(ls, off);
  if (l == 0) atomicAdd(acc, ls);
}

__global__ __launch_bounds__(256) void vq_fin(const int* __restrict__ widx,
                                              const double* __restrict__ acc,
                                              float* __restrict__ out) {
  const int t = blockIdx.x * 256 + threadIdx.x;
  if (t < 65536) out[16777217 + t] = (float)widx[t];
  if (t == 0) out[16777216] = (float)(1.25 * (*acc) * (1.0 / 16777216.0));
}

extern "C" void kernel_launch(void* const* d_in, const int* in_sizes, int n_in,
                              void* d_out, int out_size, void* d_ws, size_t ws_size,
                              hipStream_t stream) {
  const float* z = (const float*)d_in[0];
  const float* emb = (const float*)d_in[1];
  float* out = (float*)d_out;
  char* ws = (char*)d_ws;
  double* acc = (double*)(ws);
  int* widx = (int*)(ws + 64);
  float* e2 = (float*)(ws + 262208);
  float* z2 = (float*)(ws + 266304);
  int* gcnt = (int*)(ws + 528448);
  unsigned short* gcand = (unsigned short*)(ws + 790592);
  _Float16* Ef = (_Float16*)(ws + 2887744);

  hipFuncSetAttribute(reinterpret_cast<const void*>(vq_out),
                      hipFuncAttributeMaxDynamicSharedMemorySize, OUT_LDS_BYTES);

  hipMemsetAsync(ws, 0, 64, stream);
  vq_prep<<<1024, 256, 0, stream>>>(emb, Ef, e2);
  vq_z2<<<64, 256, 0, stream>>>(z, z2);
  vq_screen<<<1024, 256, 0, stream>>>(z, Ef, e2, z2, gcnt, gcand);
  vq_rescore<<<256, 256, 0, stream>>>(z, emb, e2, z2, gcnt, gcand, widx);
  vq_out<<<1024, 256, OUT_LDS_BYTES, stream>>>(z, emb, widx, out, acc);
  vq_fin<<<256, 256, 0, stream>>>(widx, acc, out);
}

// Round 6
// 375.651 us; speedup vs baseline: 4.0124x; 1.4924x over previous
//
#include <hip/hip_runtime.h>

// VectorQuantizer on MI355X — round 6: rescore v2 (LDS z-tile + 4-way candidates).
// z: (64,256,32,32) f32; emb: (1024,256) f32.
// out (f32): [0,16777216) z_q_out | [16777216] loss | [16777217,+65536) indices
//
// ws layout (bytes):
//   0        double   loss_acc                 (memset 0)
//   64       int      widx[65536]
//   262208   float    e2[1024]                 (numpy-pairwise fp32)
//   266304   float    z2[65536]                (numpy-pairwise fp32)
//   528448   int      gcnt[65536]
//   790592   ushort   gcand[65536*16]
//   2887744  _Float16 Ef[1024*256]             (f16 RNE copy of emb)

typedef _Float16 f16x8 __attribute__((ext_vector_type(8)));
typedef float f32x4 __attribute__((ext_vector_type(4)));

#define VQ_W 1.5e-3f

// fl32(v*v) with a barrier so the product cannot be contracted into a later add.
__device__ __forceinline__ float sq_rnd(float v) {
  float y = v * v;
  asm volatile("" : "+v"(y));
  return y;
}

// numpy pairwise_sum over 256 fp32 squared terms (8-accumulator blocks of 128).
__device__ float np_pw256_sq(const float* base, int stride) {
  float tot0, tot1;
  {
    const float* a = base;
    float r[8];
    #pragma unroll
    for (int j = 0; j < 8; ++j) r[j] = sq_rnd(a[j * stride]);
    #pragma unroll 1
    for (int i = 8; i < 128; i += 8) {
      #pragma unroll
      for (int j = 0; j < 8; ++j) r[j] += sq_rnd(a[(i + j) * stride]);
    }
    tot0 = ((r[0] + r[1]) + (r[2] + r[3])) + ((r[4] + r[5]) + (r[6] + r[7]));
  }
  {
    const float* a = base + 128 * stride;
    float r[8];
    #pragma unroll
    for (int j = 0; j < 8; ++j) r[j] = sq_rnd(a[j * stride]);
    #pragma unroll 1
    for (int i = 8; i < 128; i += 8) {
      #pragma unroll
      for (int j = 0; j < 8; ++j) r[j] += sq_rnd(a[(i + j) * stride]);
    }
    tot1 = ((r[0] + r[1]) + (r[2] + r[3])) + ((r[4] + r[5]) + (r[6] + r[7]));
  }
  return tot0 + tot1;
}

__global__ __launch_bounds__(256) void vq_prep(const float* __restrict__ emb,
                                               _Float16* __restrict__ Ef,
                                               float* __restrict__ e2) {
  const int g = blockIdx.x * 256 + threadIdx.x;  // 0..262143
  Ef[g] = (_Float16)emb[g];                      // RNE v_cvt_f16_f32
  if (g < 1024) e2[g] = np_pw256_sq(emb + g * 256, 1);
}

// |z|^2 per point, numpy-pairwise. 4 points/thread via float4 along hw. (r3-verified)
__global__ __launch_bounds__(256) void vq_z2(const float* __restrict__ z,
                                             float* __restrict__ z2) {
  const int t4 = blockIdx.x * 256 + threadIdx.x;  // 0..16383
  const int n0 = t4 * 4;
  const int bb = n0 >> 10, hw = n0 & 1023;
  const float* zp = z + bb * 262144 + hw;
  float r0[4][8], r1[4][8];
  #pragma unroll
  for (int p = 0; p < 4; ++p)
    #pragma unroll
    for (int j = 0; j < 8; ++j) { r0[p][j] = 0.f; r1[p][j] = 0.f; }
  #pragma unroll 1
  for (int d8 = 0; d8 < 128; d8 += 8) {
    #pragma unroll
    for (int j = 0; j < 8; ++j) {
      const float4 v = *(const float4*)&zp[(d8 + j) * 1024];
      r0[0][j] += sq_rnd(v.x); r0[1][j] += sq_rnd(v.y);
      r0[2][j] += sq_rnd(v.z); r0[3][j] += sq_rnd(v.w);
    }
  }
  #pragma unroll 1
  for (int d8 = 128; d8 < 256; d8 += 8) {
    #pragma unroll
    for (int j = 0; j < 8; ++j) {
      const float4 v = *(const float4*)&zp[(d8 + j) * 1024];
      r1[0][j] += sq_rnd(v.x); r1[1][j] += sq_rnd(v.y);
      r1[2][j] += sq_rnd(v.z); r1[3][j] += sq_rnd(v.w);
    }
  }
  #pragma unroll
  for (int p = 0; p < 4; ++p) {
    const float t0 = ((r0[p][0] + r0[p][1]) + (r0[p][2] + r0[p][3])) +
                     ((r0[p][4] + r0[p][5]) + (r0[p][6] + r0[p][7]));
    const float t1 = ((r1[p][0] + r1[p][1]) + (r1[p][2] + r1[p][3])) +
                     ((r1[p][4] + r1[p][5]) + (r1[p][6] + r1[p][7]));
    z2[n0 + p] = t0 + t1;
  }
}

// Screening: f16 MFMA, block = 64 points x all 1024 codes (8 chunks of 128).
// (r5-verified) A resident in LDS, rows XOR-swizzled; B staged per k-step with
// matching XOR swizzle. s~ = fl(fl(z2+e2) - 2*dot~); cand: s~ <= runmin + W.
__global__ __launch_bounds__(256, 3) void vq_screen(
    const float* __restrict__ z, const _Float16* __restrict__ Ef,
    const float* __restrict__ e2, const float* __restrict__ z2,
    int* __restrict__ gcnt, unsigned short* __restrict__ gcand) {
  __shared__ __align__(16) char smem[51712];
  // [0,32768) A; [32768,49152) B; 49152 runminU[64]; 49408 cnt[64]; 49664 cand[64][16]
  unsigned* runminU = (unsigned*)(smem + 49152);
  int* cnt = (int*)(smem + 49408);
  unsigned short* cand = (unsigned short*)(smem + 49664);

  const int tid = threadIdx.x;
  const int blk = blockIdx.x;
  const int n0 = blk * 64;
  const int bb = blk >> 4;
  const int hw0 = (blk & 15) * 64;
  const float* zb = z + bb * 262144 + hw0;

  if (tid < 64) { runminU[tid] = 0x7F800000u; cnt[tid] = 0; }

  {  // A stage: convert z tile to f16, swizzled rows (one-time)
    const int p = tid & 63, dh = tid >> 6;
    #pragma unroll
    for (int dq = 0; dq < 8; ++dq) {
      const int d0 = dh * 64 + dq * 8;
      f16x8 hv;
      #pragma unroll
      for (int j = 0; j < 8; ++j) hv[j] = (_Float16)zb[(d0 + j) * 1024 + p];
      *(f16x8*)&smem[p * 512 + ((d0 * 2) ^ ((p & 7) * 16))] = hv;
    }
  }

  const int l = tid & 63;
  const int ln = l & 15;
  const int q = l >> 4;
  const int wc = tid >> 6;        // col-wave: cols wc*32 .. +32
  const int xr = (l & 7) * 16;

  float z2r[4][4];
  #pragma unroll
  for (int fi = 0; fi < 4; ++fi)
    #pragma unroll
    for (int rg = 0; rg < 4; ++rg)
      z2r[fi][rg] = z2[n0 + fi * 16 + q * 4 + rg];

  f32x4 acc[4][2];
  #pragma unroll
  for (int fi = 0; fi < 4; ++fi)
    #pragma unroll
    for (int fj = 0; fj < 2; ++fj) acc[fi][fj] = (f32x4){0.f, 0.f, 0.f, 0.f};

  for (int cc = 0; cc < 8; ++cc) {
    for (int ks = 0; ks < 4; ++ks) {
      __syncthreads();
      #pragma unroll
      for (int it = 0; it < 4; ++it) {  // stage B tile 128 codes x 64 k (swizzled)
        const int c2 = it * 256 + tid;
        const int r = c2 >> 3, i = c2 & 7;
        const int isw = i ^ (r & 7);
        const f16x8 ev =
            *(const f16x8*)&Ef[(cc * 128 + r) * 256 + ks * 64 + isw * 8];
        *(f16x8*)&smem[32768 + r * 128 + i * 16] = ev;  // pos i <- octet i^(r&7)
      }
      __syncthreads();
      #pragma unroll
      for (int sl = 0; sl < 2; ++sl) {
        const int cb = (sl * 64 + q * 16) ^ xr;
        f16x8 aF[4], bF[2];
        #pragma unroll
        for (int fi = 0; fi < 4; ++fi)
          aF[fi] = *(const f16x8*)&smem[(fi * 16 + ln) * 512 + ks * 128 + cb];
        #pragma unroll
        for (int fj = 0; fj < 2; ++fj)
          bF[fj] = *(const f16x8*)&smem[32768 + (wc * 32 + fj * 16 + ln) * 128 + cb];
        #pragma unroll
        for (int fi = 0; fi < 4; ++fi)
          #pragma unroll
          for (int fj = 0; fj < 2; ++fj)
            acc[fi][fj] = __builtin_amdgcn_mfma_f32_16x16x32_f16(
                aF[fi], bF[fj], acc[fi][fj], 0, 0, 0);
      }
    }
    // epilogue: scores, running row-min, candidate collection
    const int c0 = cc * 128 + wc * 32 + ln;
    const float e2v0 = e2[c0];
    const float e2v1 = e2[c0 + 16];
    float sv[4][2][4];
    #pragma unroll
    for (int fi = 0; fi < 4; ++fi)
      #pragma unroll
      for (int rg = 0; rg < 4; ++rg) {
        sv[fi][0][rg] = fmaf(-2.f, acc[fi][0][rg], z2r[fi][rg] + e2v0);
        sv[fi][1][rg] = fmaf(-2.f, acc[fi][1][rg], z2r[fi][rg] + e2v1);
      }
    #pragma unroll
    for (int fi = 0; fi < 4; ++fi)
      #pragma unroll
      for (int rg = 0; rg < 4; ++rg) {
        float rm = fminf(sv[fi][0][rg], sv[fi][1][rg]);
        rm = fminf(rm, __shfl_xor(rm, 1));
        rm = fminf(rm, __shfl_xor(rm, 2));
        rm = fminf(rm, __shfl_xor(rm, 4));
        rm = fminf(rm, __shfl_xor(rm, 8));
        if (ln == 0)
          atomicMin(&runminU[fi * 16 + q * 4 + rg], __float_as_uint(rm));
      }
    __syncthreads();
    #pragma unroll
    for (int fi = 0; fi < 4; ++fi)
      #pragma unroll
      for (int rg = 0; rg < 4; ++rg) {
        const int row = fi * 16 + q * 4 + rg;
        const float thr = __uint_as_float(runminU[row]) + VQ_W;
        #pragma unroll
        for (int fj = 0; fj < 2; ++fj)
          if (sv[fi][fj][rg] <= thr) {
            const int slot = atomicAdd(&cnt[row], 1);
            if (slot < 16) cand[row * 16 + slot] = (unsigned short)(c0 + fj * 16);
          }
      }
    #pragma unroll
    for (int fi = 0; fi < 4; ++fi)
      #pragma unroll
      for (int fj = 0; fj < 2; ++fj) acc[fi][fj] = (f32x4){0.f, 0.f, 0.f, 0.f};
  }
  __syncthreads();
  if (tid < 64) gcnt[n0 + tid] = cnt[tid];
  {
    const int rr = tid >> 2, si = (tid & 3) * 4;
    *(uint2*)&gcand[(n0 + rr) * 16 + si] = *(const uint2*)&cand[rr * 16 + si];
  }
}

// Rescore v2: block = 64 points, z-tile staged to LDS (bit-identical fp32),
// 4 threads per point split candidates; merge via LDS u64 atomicMin on
// (score_bits<<10)|k  (positive scores -> bit-monotone; tie -> lowest k).
// Exact chain semantics unchanged from r3/r5-verified sequential fmaf.
#define RES_LDS_BYTES (65792 + 512)
__global__ __launch_bounds__(256) void vq_rescore(
    const float* __restrict__ z, const float* __restrict__ emb,
    const float* __restrict__ e2, const float* __restrict__ z2,
    const int* __restrict__ gcnt, const unsigned short* __restrict__ gcand,
    int* __restrict__ widx) {
  extern __shared__ __align__(16) char rsmem[];
  float* zt = (float*)rsmem;                              // [64][257]
  unsigned long long* best = (unsigned long long*)(rsmem + 65792);  // [64]

  const int tid = threadIdx.x;
  const int w = tid >> 6;   // candidate lane 0..3
  const int l = tid & 63;   // point 0..63
  const int n0 = blockIdx.x << 6;
  const int bb = n0 >> 10, hw0 = n0 & 1023;
  const int n = n0 + l;

  const int c = gcnt[n];
  // Block-uniform early exit: every wave sees l=0..63, same gcnt values.
  if (!__any(c >= 2)) {
    if (w == 0) widx[n] = gcand[n * 16];
    return;
  }

  {  // stage z tile: wave w loads d = it*4 + w; 256B coalesced per instr.
    const float* zb = z + bb * 262144 + hw0;
    #pragma unroll 8
    for (int it = 0; it < 64; ++it) {
      const int d = it * 4 + w;
      zt[l * 257 + d] = zb[d * 1024 + l];  // banks (l+d)%32: conflict-free
    }
  }
  if (tid < 64) best[tid] = ~0ULL;
  __syncthreads();

  if (c >= 2) {
    const float z2n = z2[n];
    const float* zrow = &zt[l * 257];
    if (c <= 16) {
      for (int s = w; s < c; s += 4) {
        const int k = gcand[n * 16 + s];
        const float* ep = emb + k * 256;
        float a = 0.f;
        #pragma unroll 4
        for (int d = 0; d < 256; ++d) a = fmaf(zrow[d], ep[d], a);
        const float sv = fmaf(-2.f, a, z2n + e2[k]);
        const unsigned long long key =
            ((unsigned long long)__float_as_uint(sv) << 10) | (unsigned)k;
        atomicMin(&best[l], key);
      }
    } else {  // overflow fallback: exact full scan, same min/lowest-k semantics
      for (int k = w; k < 1024; k += 4) {
        const float* ep = emb + k * 256;
        float a = 0.f;
        #pragma unroll 4
        for (int d = 0; d < 256; ++d) a = fmaf(zrow[d], ep[d], a);
        const float sv = fmaf(-2.f, a, z2n + e2[k]);
        const unsigned long long key =
            ((unsigned long long)__float_as_uint(sv) << 10) | (unsigned)k;
        atomicMin(&best[l], key);
      }
    }
  }
  __syncthreads();
  if (tid < 64) {
    const int cc = gcnt[n0 + tid];
    widx[n0 + tid] = (cc == 1) ? (int)gcand[(n0 + tid) * 16]
                               : (int)(best[tid] & 1023ULL);
  }
}

// Output + loss (r3-verified). Gather 64 emb rows into LDS row-coalesced, then
// transpose-read (stride 260) + coalesced global write.
#define OUT_LDS_BYTES 66560
__global__ __launch_bounds__(256) void vq_out(const float* __restrict__ z,
                                              const float* __restrict__ emb,
                                              const int* __restrict__ widx,
                                              float* __restrict__ out,
                                              double* __restrict__ acc) {
  extern __shared__ float rows[];  // [64][260]
  const int tid = threadIdx.x;
  const int w = tid >> 6, l = tid & 63;
  const int n0 = blockIdx.x << 6;
  const int bb = n0 >> 10, hw0 = n0 & 1023;

  #pragma unroll 4
  for (int rr = 0; rr < 16; ++rr) {
    const int r = rr * 4 + w;
    const int idx = widx[n0 + r];
    const float4 ev = *(const float4*)&emb[idx * 256 + l * 4];
    *(float4*)&rows[r * 260 + l * 4] = ev;
  }
  __syncthreads();

  const int zofs = bb * 262144 + hw0 + l;
  const float* zp = z + zofs;
  float* op = out + zofs;
  double ls = 0.0;
  #pragma unroll 2
  for (int i16 = 0; i16 < 16; ++i16) {
    const int d4 = w * 64 + i16 * 4;
    const float4 q4 = *(const float4*)&rows[l * 260 + d4];
    #pragma unroll
    for (int e = 0; e < 4; ++e) {
      const int d = d4 + e;
      const float zv = zp[d * 1024];
      const float qv = ((const float*)&q4)[e];
      float df = qv - zv;
      asm volatile("" : "+v"(df));
      op[d * 1024] = zv + df;  // fl(z + fl(z_q - z))
      ls += (double)df * df;
    }
  }
  #pragma unroll
  for (int off = 32; off > 0; off >>= 1) ls += __shfl_down(ls, off);
  if (l == 0) atomicAdd(acc, ls);
}

__global__ __launch_bounds__(256) void vq_fin(const int* __restrict__ widx,
                                              const double* __restrict__ acc,
                                              float* __restrict__ out) {
  const int t = blockIdx.x * 256 + threadIdx.x;
  if (t < 65536) out[16777217 + t] = (float)widx[t];
  if (t == 0) out[16777216] = (float)(1.25 * (*acc) * (1.0 / 16777216.0));
}

extern "C" void kernel_launch(void* const* d_in, const int* in_sizes, int n_in,
                              void* d_out, int out_size, void* d_ws, size_t ws_size,
                              hipStream_t stream) {
  const float* z = (const float*)d_in[0];
  const float* emb = (const float*)d_in[1];
  float* out = (float*)d_out;
  char* ws = (char*)d_ws;
  double* acc = (double*)(ws);
  int* widx = (int*)(ws + 64);
  float* e2 = (float*)(ws + 262208);
  float* z2 = (float*)(ws + 266304);
  int* gcnt = (int*)(ws + 528448);
  unsigned short* gcand = (unsigned short*)(ws + 790592);
  _Float16* Ef = (_Float16*)(ws + 2887744);

  hipFuncSetAttribute(reinterpret_cast<const void*>(vq_out),
                      hipFuncAttributeMaxDynamicSharedMemorySize, OUT_LDS_BYTES);
  hipFuncSetAttribute(reinterpret_cast<const void*>(vq_rescore),
                      hipFuncAttributeMaxDynamicSharedMemorySize, RES_LDS_BYTES);

  hipMemsetAsync(ws, 0, 64, stream);
  vq_prep<<<1024, 256, 0, stream>>>(emb, Ef, e2);
  vq_z2<<<64, 256, 0, stream>>>(z, z2);
  vq_screen<<<1024, 256, 0, stream>>>(z, Ef, e2, z2, gcnt, gcand);
  vq_rescore<<<1024, 256, RES_LDS_BYTES, stream>>>(z, emb, e2, z2, gcnt, gcand, widx);
  vq_out<<<1024, 256, OUT_LDS_BYTES, stream>>>(z, emb, widx, out, acc);
  vq_fin<<<256, 256, 0, stream>>>(widx, acc, out);
}